// Round 11
// baseline (389.353 us; speedup 1.0000x reference)
//
#include <hip/hip_runtime.h>
#include <hip/hip_bf16.h>

// out[n,d] = b[d] + pk[n,d] + max_m ok[n,m,d]
//   pk = p @ Wp^T  (2048x1024,  K=1024)   -- small 128-tile kernel
//   ok = o @ Wo^T  (65536x1024, K=1024)   -- fused-convert 256^2 GEMM
// R11 = R8 with full read-ahead at constant register state:
//   ph4(t) prefetches af(t+1)+b01(t+1) from the other buffer (dead regs);
//   ph1 reads only b23; ph2 reads af2. Derived lgkm waits (4/15/0), 4
//   barriers/tile. vmcnt ledger: ph2 VMCNT(4) retires A(t+1); ph4
//   VMCNT(12) retires B(t+1) (needed by ph4's own b01 prefetch);
//   t=14: ph4 VMCNT(0).

#define NN 2048
#define MM 32
#define CC 1024

typedef __attribute__((ext_vector_type(8))) __bf16 bf16x8;
typedef __attribute__((ext_vector_type(4))) float f32x4;
typedef __attribute__((ext_vector_type(8))) unsigned short u16x8;
typedef __attribute__((ext_vector_type(4))) unsigned short u16x4;

__device__ inline unsigned short f2bf(float f) {
  union { __hip_bfloat16 h; unsigned short u; } v;
  v.h = __float2bfloat16(f);
  return v.u;
}

__device__ inline void gload_lds16(const void* g, void* l) {
  __builtin_amdgcn_global_load_lds(
      (const __attribute__((address_space(1))) void*)g,
      (__attribute__((address_space(3))) void*)l, 16, 0, 0);
}

// ---- convert person_features + split W into Wp/Wo (bf16) ----
__global__ void conv_pw(const float* __restrict__ p, const float* __restrict__ W,
                        unsigned short* __restrict__ pd,
                        unsigned short* __restrict__ wp,
                        unsigned short* __restrict__ wo) {
  const int PG = (NN * CC) / 8;
  const int WG = (CC * 2 * CC) / 8;
  int i = blockIdx.x * blockDim.x + threadIdx.x;
  int stride = gridDim.x * blockDim.x;
  for (; i < PG + WG; i += stride) {
    if (i < PG) {
      const float4* s = reinterpret_cast<const float4*>(p) + (size_t)i * 2;
      float4 a = s[0], b = s[1];
      u16x8 r;
      r[0] = f2bf(a.x); r[1] = f2bf(a.y); r[2] = f2bf(a.z); r[3] = f2bf(a.w);
      r[4] = f2bf(b.x); r[5] = f2bf(b.y); r[6] = f2bf(b.z); r[7] = f2bf(b.w);
      *reinterpret_cast<u16x8*>(pd + (size_t)i * 8) = r;
    } else {
      int f = i - PG;
      int e = f * 8;
      int d = e >> 11;
      int cc = e & 2047;
      const float4* s = reinterpret_cast<const float4*>(W) + (size_t)f * 2;
      float4 a = s[0], b = s[1];
      u16x8 r;
      r[0] = f2bf(a.x); r[1] = f2bf(a.y); r[2] = f2bf(a.z); r[3] = f2bf(a.w);
      r[4] = f2bf(b.x); r[5] = f2bf(b.y); r[6] = f2bf(b.z); r[7] = f2bf(b.w);
      unsigned short* o = (cc < CC) ? (wp + (size_t)d * CC + cc)
                                    : (wo + (size_t)d * CC + (cc - CC));
      *reinterpret_cast<u16x8*>(o) = r;
    }
  }
}

// ---- small 128x128 GEMM for pk+b ----
__global__ void gemm_pk(const unsigned short* __restrict__ A,
                        const unsigned short* __restrict__ B,
                        const float* __restrict__ bvec,
                        float* __restrict__ out) {
  __shared__ unsigned short As[128 * 64];
  __shared__ unsigned short Bs[128 * 64];

  int nb = gridDim.x;
  int chunk = nb >> 3;
  int obid = blockIdx.x;
  int vb = (obid & 7) * chunk + (obid >> 3);
  int bcol = vb & 7;
  int brow = vb >> 3;

  int tid = threadIdx.x;
  int l = tid & 63;
  int wid = tid >> 6;
  int wr = wid >> 1, wc = wid & 1;
  int lr = l & 15;
  int lk = (l >> 4) << 3;

  const unsigned short* gA = A + (size_t)brow * 128 * CC;
  const unsigned short* gB = B + (size_t)bcol * 128 * CC;

  f32x4 acc[4][4] = {};

  for (int kt = 0; kt < 16; ++kt) {
    int k0 = kt * 64;
#pragma unroll
    for (int j = 0; j < 4; ++j) {
      int f = (j * 256 + tid) * 8;
      int r = f >> 6;
      int c = f & 63;
      gload_lds16(gA + (size_t)r * CC + k0 + c, &As[f]);
      gload_lds16(gB + (size_t)r * CC + k0 + c, &Bs[f]);
    }
    __syncthreads();
#pragma unroll
    for (int kk = 0; kk < 2; ++kk) {
      bf16x8 af[4], bfr[4];
#pragma unroll
      for (int mi = 0; mi < 4; ++mi)
        af[mi] = *reinterpret_cast<const bf16x8*>(
            &As[(wr * 64 + mi * 16 + lr) * 64 + kk * 32 + lk]);
#pragma unroll
      for (int ni = 0; ni < 4; ++ni)
        bfr[ni] = *reinterpret_cast<const bf16x8*>(
            &Bs[(wc * 64 + ni * 16 + lr) * 64 + kk * 32 + lk]);
#pragma unroll
      for (int mi = 0; mi < 4; ++mi)
#pragma unroll
        for (int ni = 0; ni < 4; ++ni)
          acc[mi][ni] = __builtin_amdgcn_mfma_f32_16x16x32_bf16(
              af[mi], bfr[ni], acc[mi][ni], 0, 0, 0);
    }
    __syncthreads();
  }

#pragma unroll
  for (int mi = 0; mi < 4; ++mi) {
    int row = brow * 128 + wr * 64 + mi * 16 + (l >> 4) * 4;
#pragma unroll
    for (int ni = 0; ni < 4; ++ni) {
      int col = bcol * 128 + wc * 64 + ni * 16 + lr;
      float bb = bvec[col];
#pragma unroll
      for (int r = 0; r < 4; ++r)
        out[(size_t)(row + r) * CC + col] = acc[mi][ni][r] + bb;
    }
  }
}

// ==================== 256x256 fused main GEMM, read-ahead (R11) =============
// LDS: 2 bufs x (A 32KB @ +0, B 32KB @ +32768); buf k at k*65536. 128KB.
// Swizzle: LDS cell (row, chunk16B) holds global (row, chunk ^ (row&7)).

#define BARRIER                                      \
  do {                                               \
    asm volatile("" ::: "memory");                   \
    __builtin_amdgcn_s_barrier();                    \
    asm volatile("" ::: "memory");                   \
  } while (0)

#define LGKM(n) asm volatile("s_waitcnt lgkmcnt(" #n ")" ::: "memory")
#define VMCNT(n) asm volatile("s_waitcnt vmcnt(" #n ")" ::: "memory")

#define STAGE(gsrc, bufidx, isB, h, k0)                                       \
  do {                                                                        \
    _Pragma("unroll") for (int ii = 0; ii < 2; ++ii)                          \
        gload_lds16(gsrc + (size_t)((h) * 128 + ii * 64 + rr) * CC + (k0) + sc, \
                    lds + (bufidx) * 65536 + (isB) * 32768 + (h) * 16384 +    \
                        ii * 8192 + tid * 16);                                \
  } while (0)

// coalesced A issue: instruction j covers rows 32j..32j+31, lane-contiguous.
#define ISSUE_A(aI, k0)                                                       \
  do {                                                                        \
    _Pragma("unroll") for (int j = 0; j < 8; ++j)                             \
        aI[j] = *reinterpret_cast<const float4*>(                             \
            gAf + (size_t)(j * 32 + arow0) * CC + (k0) + ac4 * 4);            \
  } while (0)

// convert + swizzled ds_write_b64 into buffer bufidx's A region
#define CVT_WRITE_A(aC, bufidx)                                               \
  do {                                                                        \
    _Pragma("unroll") for (int j = 0; j < 8; ++j) {                           \
      u16x4 r;                                                                \
      r[0] = f2bf(aC[j].x); r[1] = f2bf(aC[j].y);                             \
      r[2] = f2bf(aC[j].z); r[3] = f2bf(aC[j].w);                             \
      *reinterpret_cast<u16x4*>(lds + (bufidx) * 65536 +                      \
                                (j * 32 + arow0) * 128 + aswz) = r;           \
    }                                                                         \
  } while (0)

#define DSREAD_A(bufo, mq, AF)                                                \
  do {                                                                        \
    _Pragma("unroll") for (int i = 0; i < 4; ++i) {                           \
      AF[i][0] = *(const bf16x8*)(lds + (bufo) + a_base0 + (mq) * 8192 + i * 2048); \
      AF[i][1] = *(const bf16x8*)(lds + (bufo) + a_base1 + (mq) * 8192 + i * 2048); \
    }                                                                         \
  } while (0)

// B fragments ni=0,1 (b01) or ni=2,3 (b23)
#define DSREAD_B01(bufo)                                                      \
  do {                                                                        \
    _Pragma("unroll") for (int j = 0; j < 2; ++j) {                           \
      b01[j][0] = *(const bf16x8*)(lds + (bufo) + b_base0 + j * 2048);        \
      b01[j][1] = *(const bf16x8*)(lds + (bufo) + b_base1 + j * 2048);        \
    }                                                                         \
  } while (0)

#define DSREAD_B23(bufo)                                                      \
  do {                                                                        \
    _Pragma("unroll") for (int j = 0; j < 2; ++j) {                           \
      b23[j][0] = *(const bf16x8*)(lds + (bufo) + b_base0 + (2 + j) * 2048);  \
      b23[j][1] = *(const bf16x8*)(lds + (bufo) + b_base1 + (2 + j) * 2048);  \
    }                                                                         \
  } while (0)

#define MFMA16(AF, mq, nq, BF)                                                \
  do {                                                                        \
    __builtin_amdgcn_s_setprio(1);                                            \
    _Pragma("unroll") for (int i = 0; i < 4; ++i)                             \
        _Pragma("unroll") for (int j = 0; j < 2; ++j) {                       \
      acc[(mq) * 4 + i][(nq) * 2 + j] = __builtin_amdgcn_mfma_f32_16x16x32_bf16( \
          AF[i][0], BF[j][0], acc[(mq) * 4 + i][(nq) * 2 + j], 0, 0, 0);      \
      acc[(mq) * 4 + i][(nq) * 2 + j] = __builtin_amdgcn_mfma_f32_16x16x32_bf16( \
          AF[i][1], BF[j][1], acc[(mq) * 4 + i][(nq) * 2 + j], 0, 0, 0);      \
    }                                                                         \
    __builtin_amdgcn_s_setprio(0);                                            \
  } while (0)

// One K-tile t. bufo=(t&1)*65536, bufn=((t+1)&1)*65536, bufn_idx=(t+1)&1.
// Entering: af + b01 hold tile t's fragments (prefetched at t-1.ph4);
// lgkm outstanding = 12 (those prefetch reads); vmem = [A(t+1):8, B(t+1):4].
#define TILE(t, bufo, bufn, bufn_idx)                                         \
  do {                                                                        \
    /* ph1 */                                                                 \
    DSREAD_B23(bufo);                                                         \
    LGKM(4);                       /* af,b01 ready (leaves b23's 4) */        \
    MFMA16(af, 0, 0, b01);                                                    \
    BARRIER;                                                                  \
    /* ph2 */                                                                 \
    if ((t) + 1 < 16) {                                                       \
      VMCNT(4);                    /* retire A(t+1); leaves B(t+1)4 */        \
      CVT_WRITE_A(aL, bufn_idx);                                              \
      if ((t) + 2 < 16) ISSUE_A(aL, ((t) + 2) * 64);                          \
    }                                                                         \
    DSREAD_A(bufo, 1, af2);                                                   \
    if ((t) + 1 < 16) { LGKM(15); } else { LGKM(8); }  /* b23 ready */        \
    MFMA16(af, 0, 1, b23);                                                    \
    BARRIER;                                                                  \
    /* ph3 */                                                                 \
    if ((t) + 2 < 16) {                                                       \
      STAGE(gB, ((t) & 1), 1, 0, ((t) + 2) * 64);                             \
      STAGE(gB, ((t) & 1), 1, 1, ((t) + 2) * 64);                             \
    }                                                                         \
    LGKM(0);                       /* af2 ready, writes drained */            \
    MFMA16(af2, 1, 0, b01);                                                   \
    BARRIER;                                                                  \
    /* ph4 */                                                                 \
    if ((t) <= 13) { VMCNT(12); }  /* retire B(t+1) for b01 prefetch */       \
    else if ((t) == 14) { VMCNT(0); }                                         \
    if ((t) + 1 < 16) {                                                       \
      DSREAD_A(bufn, 0, af);       /* prefetch tile t+1 */                    \
      DSREAD_B01(bufn);                                                       \
    }                                                                         \
    MFMA16(af2, 1, 1, b23);        /* all operands in regs */                 \
    BARRIER;                                                                  \
  } while (0)

__global__ __launch_bounds__(512, 2) void gemm_fused(
    const float* __restrict__ A,
    const unsigned short* __restrict__ B,
    const float* __restrict__ pkb,
    float* __restrict__ out) {
  __shared__ char lds[131072];

  int obid = blockIdx.x;                    // 1024 blocks
  int vb = (obid & 7) * 128 + (obid >> 3);  // XCD-contiguous (1024 % 8 == 0)
  int bcol = vb & 3;                        // 4 col tiles
  int brow = vb >> 2;                       // 256 row tiles

  int tid = threadIdx.x;
  int l = tid & 63;
  int wid = tid >> 6;
  int wr = wid >> 2;   // 0..1
  int wc = wid & 3;    // 0..3
  int lr = l & 15;
  int g = l >> 4;      // 0..3

  const float* gAf = A + (size_t)brow * 256 * CC;
  const unsigned short* gB = B + (size_t)bcol * 256 * CC;

  // B staging addressing (linear LDS dest, inverse-swizzled global source)
  int rr = tid >> 3;
  int sc = ((tid & 7) ^ (rr & 7)) * 8;

  // A reg-staging addressing (coalesced): instr j -> row j*32+arow0, 16B col ac4
  int arow0 = tid >> 4;                      // 0..31
  int ac4 = tid & 15;                        // 16B column index (f32)
  int aswz = (((ac4 >> 1) ^ (arow0 & 7)) * 16) + (ac4 & 1) * 8;

  // ds_read byte offsets: row R, chunk (kk*4+g)^(R&7); R&7 == lr&7
  int axor = lr & 7;
  int a_base0 = (wr * 128 + lr) * 128 + ((g ^ axor) * 16);
  int a_base1 = (wr * 128 + lr) * 128 + (((4 + g) ^ axor) * 16);
  int b_base0 = 32768 + (wc * 64 + lr) * 128 + ((g ^ axor) * 16);
  int b_base1 = 32768 + (wc * 64 + lr) * 128 + (((4 + g) ^ axor) * 16);

  f32x4 acc[8][4] = {};
  bf16x8 af[4][2], af2[4][2];
  bf16x8 b01[2][2], b23[2][2];
  float4 aL[8];

  // prologue:
  //   A0[8]; B0stage[4]; vmcnt(4) retires A0; cvt+write A0 -> buf0;
  //   A1[8]; B1stage[4]; vmcnt(12) retires B0; LGKM0; BARRIER;
  //   prefetch af(0)+b01(0) [12 lgkm outstanding -> loop invariant].
  ISSUE_A(aL, 0);
  STAGE(gB, 0, 1, 0, 0);
  STAGE(gB, 0, 1, 1, 0);
  VMCNT(4);
  CVT_WRITE_A(aL, 0);
  ISSUE_A(aL, 64);
  STAGE(gB, 1, 1, 0, 64);
  STAGE(gB, 1, 1, 1, 64);
  VMCNT(12);
  LGKM(0); BARRIER;
  DSREAD_A(0, 0, af);
  DSREAD_B01(0);

#pragma unroll 1
  for (int tt = 0; tt < 16; tt += 2) {
    TILE(tt, 0, 65536, 1);
    TILE(tt + 1, 65536, 0, 0);
  }

  // fused epilogue: max over 32 consecutive A-rows per n, + pkb
  int colb = bcol * 256 + wc * 64;
#pragma unroll
  for (int a = 0; a < 4; ++a) {
    int n = brow * 8 + wr * 4 + a;
#pragma unroll
    for (int ni = 0; ni < 4; ++ni) {
      float v = -3.402823466e38f;
#pragma unroll
      for (int mi = 2 * a; mi < 2 * a + 2; ++mi)
#pragma unroll
        for (int r = 0; r < 4; ++r) v = fmaxf(v, acc[mi][ni][r]);
      v = fmaxf(v, __shfl_xor(v, 16));
      v = fmaxf(v, __shfl_xor(v, 32));
      if (l < 16) {
        int col = colb + ni * 16 + l;
        out[(size_t)n * CC + col] = v + pkb[(size_t)n * CC + col];
      }
    }
  }
}

extern "C" void kernel_launch(void* const* d_in, const int* in_sizes, int n_in,
                              void* d_out, int out_size, void* d_ws, size_t ws_size,
                              hipStream_t stream) {
  const float* p = (const float*)d_in[0];   // (N, C, 1, 1)
  const float* o = (const float*)d_in[1];   // (N, M, C, 1, 1)
  const float* W = (const float*)d_in[5];   // (C, 2C)
  const float* b = (const float*)d_in[6];   // (C,)
  float* out = (float*)d_out;               // (N, C, 1, 1)

  char* ws = (char*)d_ws;
  unsigned short* p_bf  = (unsigned short*)ws;                 // 4 MB
  unsigned short* wp_bf = (unsigned short*)(ws + 4194304);     // 2 MB
  unsigned short* wo_bf = (unsigned short*)(ws + 6291456);     // 2 MB
  float*          pkb   = (float*)(ws + 8388608);              // 8 MB

  conv_pw<<<512, 256, 0, stream>>>(p, W, p_bf, wp_bf, wo_bf);
  gemm_pk<<<128, 256, 0, stream>>>(p_bf, wp_bf, b, pkb);
  gemm_fused<<<1024, 512, 0, stream>>>(o, wo_bf, pkb, out);
}

// Round 12
// 220.262 us; speedup vs baseline: 1.7677x; 1.7677x over previous
//
#include <hip/hip_runtime.h>
#include <hip/hip_bf16.h>

// out[n,d] = b[d] + pk[n,d] + max_m ok[n,m,d]
//   pk = p @ Wp^T  (2048x1024,  K=1024)   -- small 128-tile kernel
//   ok = o @ Wo^T  (65536x1024, K=1024)   -- fused-convert 128^2 BK=32 GEMM
// R12: 128x128 tile, BK=32, 256 thr (4 waves of 64x64), LDS 32KB
// (A dbuf 2x8KB + B dbuf 2x8KB) -> 4 blocks/CU = 16 waves/CU for
// cross-block latency overlap (acc only 64 VGPR/wave -> fits 128 cap).
// A (f32) reg-staged coalesced (aL[4]) -> cvt -> swizzled ds_write_b64.
// B staged via global_load_lds (inverse-swizzled source). 1 barrier/tile.
// vmcnt ledger: mid VMCNT(2) retires A(t+1); end VMCNT(4) retires B(t+1);
// t=30 end VMCNT(0). 64B rows -> 2-bit chunk swizzle (chunk ^= row&3).

#define NN 2048
#define MM 32
#define CC 1024

typedef __attribute__((ext_vector_type(8))) __bf16 bf16x8;
typedef __attribute__((ext_vector_type(4))) float f32x4;
typedef __attribute__((ext_vector_type(8))) unsigned short u16x8;
typedef __attribute__((ext_vector_type(4))) unsigned short u16x4;

__device__ inline unsigned short f2bf(float f) {
  union { __hip_bfloat16 h; unsigned short u; } v;
  v.h = __float2bfloat16(f);
  return v.u;
}

__device__ inline void gload_lds16(const void* g, void* l) {
  __builtin_amdgcn_global_load_lds(
      (const __attribute__((address_space(1))) void*)g,
      (__attribute__((address_space(3))) void*)l, 16, 0, 0);
}

// ---- convert person_features + split W into Wp/Wo (bf16) ----
__global__ void conv_pw(const float* __restrict__ p, const float* __restrict__ W,
                        unsigned short* __restrict__ pd,
                        unsigned short* __restrict__ wp,
                        unsigned short* __restrict__ wo) {
  const int PG = (NN * CC) / 8;
  const int WG = (CC * 2 * CC) / 8;
  int i = blockIdx.x * blockDim.x + threadIdx.x;
  int stride = gridDim.x * blockDim.x;
  for (; i < PG + WG; i += stride) {
    if (i < PG) {
      const float4* s = reinterpret_cast<const float4*>(p) + (size_t)i * 2;
      float4 a = s[0], b = s[1];
      u16x8 r;
      r[0] = f2bf(a.x); r[1] = f2bf(a.y); r[2] = f2bf(a.z); r[3] = f2bf(a.w);
      r[4] = f2bf(b.x); r[5] = f2bf(b.y); r[6] = f2bf(b.z); r[7] = f2bf(b.w);
      *reinterpret_cast<u16x8*>(pd + (size_t)i * 8) = r;
    } else {
      int f = i - PG;
      int e = f * 8;
      int d = e >> 11;
      int cc = e & 2047;
      const float4* s = reinterpret_cast<const float4*>(W) + (size_t)f * 2;
      float4 a = s[0], b = s[1];
      u16x8 r;
      r[0] = f2bf(a.x); r[1] = f2bf(a.y); r[2] = f2bf(a.z); r[3] = f2bf(a.w);
      r[4] = f2bf(b.x); r[5] = f2bf(b.y); r[6] = f2bf(b.z); r[7] = f2bf(b.w);
      unsigned short* o = (cc < CC) ? (wp + (size_t)d * CC + cc)
                                    : (wo + (size_t)d * CC + (cc - CC));
      *reinterpret_cast<u16x8*>(o) = r;
    }
  }
}

// ---- small 128x128 GEMM for pk+b ----
__global__ void gemm_pk(const unsigned short* __restrict__ A,
                        const unsigned short* __restrict__ B,
                        const float* __restrict__ bvec,
                        float* __restrict__ out) {
  __shared__ unsigned short As[128 * 64];
  __shared__ unsigned short Bs[128 * 64];

  int nb = gridDim.x;
  int chunk = nb >> 3;
  int obid = blockIdx.x;
  int vb = (obid & 7) * chunk + (obid >> 3);
  int bcol = vb & 7;
  int brow = vb >> 3;

  int tid = threadIdx.x;
  int l = tid & 63;
  int wid = tid >> 6;
  int wr = wid >> 1, wc = wid & 1;
  int lr = l & 15;
  int lk = (l >> 4) << 3;

  const unsigned short* gA = A + (size_t)brow * 128 * CC;
  const unsigned short* gB = B + (size_t)bcol * 128 * CC;

  f32x4 acc[4][4] = {};

  for (int kt = 0; kt < 16; ++kt) {
    int k0 = kt * 64;
#pragma unroll
    for (int j = 0; j < 4; ++j) {
      int f = (j * 256 + tid) * 8;
      int r = f >> 6;
      int c = f & 63;
      gload_lds16(gA + (size_t)r * CC + k0 + c, &As[f]);
      gload_lds16(gB + (size_t)r * CC + k0 + c, &Bs[f]);
    }
    __syncthreads();
#pragma unroll
    for (int kk = 0; kk < 2; ++kk) {
      bf16x8 af[4], bfr[4];
#pragma unroll
      for (int mi = 0; mi < 4; ++mi)
        af[mi] = *reinterpret_cast<const bf16x8*>(
            &As[(wr * 64 + mi * 16 + lr) * 64 + kk * 32 + lk]);
#pragma unroll
      for (int ni = 0; ni < 4; ++ni)
        bfr[ni] = *reinterpret_cast<const bf16x8*>(
            &Bs[(wc * 64 + ni * 16 + lr) * 64 + kk * 32 + lk]);
#pragma unroll
      for (int mi = 0; mi < 4; ++mi)
#pragma unroll
        for (int ni = 0; ni < 4; ++ni)
          acc[mi][ni] = __builtin_amdgcn_mfma_f32_16x16x32_bf16(
              af[mi], bfr[ni], acc[mi][ni], 0, 0, 0);
    }
    __syncthreads();
  }

#pragma unroll
  for (int mi = 0; mi < 4; ++mi) {
    int row = brow * 128 + wr * 64 + mi * 16 + (l >> 4) * 4;
#pragma unroll
    for (int ni = 0; ni < 4; ++ni) {
      int col = bcol * 128 + wc * 64 + ni * 16 + lr;
      float bb = bvec[col];
#pragma unroll
      for (int r = 0; r < 4; ++r)
        out[(size_t)(row + r) * CC + col] = acc[mi][ni][r] + bb;
    }
  }
}

// ==================== 128x128 BK=32 fused main GEMM (R12) ===================
// LDS: Abuf[2] @ 0/8192 (128x32 bf16, 64B rows), Bbuf[2] @ 16384/24576.
// Swizzle: LDS cell (row, chunk16B c) holds logical chunk c ^ (row&3).

#define BARRIER                                      \
  do {                                               \
    asm volatile("" ::: "memory");                   \
    __builtin_amdgcn_s_barrier();                    \
    asm volatile("" ::: "memory");                   \
  } while (0)

#define LGKM0 asm volatile("s_waitcnt lgkmcnt(0)" ::: "memory")
#define VMCNT(n) asm volatile("s_waitcnt vmcnt(" #n ")" ::: "memory")

// B stage: 128x32 bf16 = 8KB; 2 x gload_lds16/thread, inverse-swz source.
#define STAGE_B(bslot, k0)                                                    \
  do {                                                                        \
    _Pragma("unroll") for (int j = 0; j < 2; ++j)                             \
        gload_lds16(gB + (size_t)(j * 64 + brr) * CC + (k0) + bsc,            \
                    lds + 16384 + (bslot) * 8192 + (j * 256 + tid) * 16);     \
  } while (0)

// A issue: 128x32 f32 = 16KB; instr j -> rows 32j.., lane-contiguous 16B.
#define ISSUE_A(aI, k0)                                                       \
  do {                                                                        \
    _Pragma("unroll") for (int j = 0; j < 4; ++j)                             \
        aI[j] = *reinterpret_cast<const float4*>(                             \
            gAf + (size_t)(j * 32 + arow0) * CC + (k0) + ac4 * 4);            \
  } while (0)

// cvt + swizzled ds_write_b64 into Abuf[aslot]
#define CVT_WRITE_A(aC, aslot)                                                \
  do {                                                                        \
    _Pragma("unroll") for (int j = 0; j < 4; ++j) {                           \
      u16x4 r;                                                                \
      r[0] = f2bf(aC[j].x); r[1] = f2bf(aC[j].y);                             \
      r[2] = f2bf(aC[j].z); r[3] = f2bf(aC[j].w);                             \
      *reinterpret_cast<u16x4*>(lds + (aslot) * 8192 +                        \
                                (j * 32 + arow0) * 64 + aswz) = r;            \
    }                                                                         \
  } while (0)

#define MFMA16X                                                               \
  do {                                                                        \
    __builtin_amdgcn_s_setprio(1);                                            \
    _Pragma("unroll") for (int mi = 0; mi < 4; ++mi)                          \
        _Pragma("unroll") for (int ni = 0; ni < 4; ++ni)                      \
            acc[mi][ni] = __builtin_amdgcn_mfma_f32_16x16x32_bf16(            \
                af[mi], bfr[ni], acc[mi][ni], 0, 0, 0);                       \
    __builtin_amdgcn_s_setprio(0);                                            \
  } while (0)

// One K-tile t (BK=32): read frags from slot, stage B(t+1)->nslot,
// cvt+write A(t+1)->nslot, issue A(t+2).
#define TILE(t, slot, nslot)                                                  \
  do {                                                                        \
    if ((t) + 1 < 32) STAGE_B(nslot, ((t) + 1) * 32);                         \
    _Pragma("unroll") for (int mi = 0; mi < 4; ++mi)                          \
        af[mi] = *(const bf16x8*)(lds + (slot) * 8192 + a_base + mi * 1024);  \
    _Pragma("unroll") for (int ni = 0; ni < 4; ++ni)                          \
        bfr[ni] = *(const bf16x8*)(lds + (slot) * 8192 + b_base + ni * 1024); \
    LGKM0;                                                                    \
    MFMA16X;                                                                  \
    if ((t) + 1 < 32) {                                                       \
      VMCNT(2);                                                               \
      CVT_WRITE_A(aL, nslot);                                                 \
      if ((t) + 2 < 32) ISSUE_A(aL, ((t) + 2) * 32);                          \
    }                                                                         \
    if ((t) <= 29) { VMCNT(4); }                                              \
    else if ((t) == 30) { VMCNT(0); }                                         \
    LGKM0;                                                                    \
    BARRIER;                                                                  \
  } while (0)

__global__ __launch_bounds__(256, 4) void gemm_fused(
    const float* __restrict__ A,
    const unsigned short* __restrict__ B,
    const float* __restrict__ pkb,
    float* __restrict__ out) {
  __shared__ char lds[32768];

  int obid = blockIdx.x;                    // 4096 blocks
  int vb = (obid & 7) * 512 + (obid >> 3);  // XCD-contiguous (4096 % 8 == 0)
  int bcol = vb & 7;                        // 8 col tiles
  int brow = vb >> 3;                       // 512 row tiles

  int tid = threadIdx.x;
  int l = tid & 63;
  int wid = tid >> 6;
  int wr = wid >> 1;   // 0..1 (M half)
  int wc = wid & 1;    // 0..1 (N half)
  int lr = l & 15;
  int g = l >> 4;      // 0..3

  const float* gAf = A + (size_t)brow * 128 * CC;
  const unsigned short* gB = B + (size_t)bcol * 128 * CC;

  // B staging: instr j -> row j*64 + brr, chunk tid&3; inverse-swz src col.
  int brr = tid >> 2;                        // 0..63
  int bsc = ((tid & 3) ^ (brr & 3)) * 8;     // source col (elements)

  // A reg-staging: instr j -> row j*32+arow0, 16B f32 col ac4 (0..7).
  int arow0 = tid >> 3;                      // 0..31
  int ac4 = tid & 7;
  int aswz = (((ac4 >> 1) ^ (arow0 & 3)) * 16) + (ac4 & 1) * 8;

  // fragment read bases: row R, logical chunk g stored at g^(R&3); R&3==lr&3.
  int axor = lr & 3;
  int a_base = (wr * 64 + lr) * 64 + ((g ^ axor) * 16);
  int b_base = 16384 + (wc * 64 + lr) * 64 + ((g ^ axor) * 16);

  f32x4 acc[4][4] = {};
  bf16x8 af[4], bfr[4];
  float4 aL[4];

  // prologue: A0[4]; B0stage[2]; vmcnt(2) retires A0; cvt+write A0 -> slot0;
  // A1[4]; vmcnt(4) retires B0 (leaves A1[4]); LGKM0; BARRIER.
  ISSUE_A(aL, 0);
  STAGE_B(0, 0);
  VMCNT(2);
  CVT_WRITE_A(aL, 0);
  ISSUE_A(aL, 32);
  VMCNT(4);
  LGKM0; BARRIER;

#pragma unroll 1
  for (int tt = 0; tt < 32; tt += 2) {
    TILE(tt, 0, 1);
    TILE(tt + 1, 1, 0);
  }

  // fused epilogue: max over 32 consecutive A-rows per n, + pkb
#pragma unroll
  for (int a = 0; a < 2; ++a) {
    int n = brow * 4 + wr * 2 + a;
#pragma unroll
    for (int ni = 0; ni < 4; ++ni) {
      float v = -3.402823466e38f;
#pragma unroll
      for (int mi = 2 * a; mi < 2 * a + 2; ++mi)
#pragma unroll
        for (int r = 0; r < 4; ++r) v = fmaxf(v, acc[mi][ni][r]);
      v = fmaxf(v, __shfl_xor(v, 16));
      v = fmaxf(v, __shfl_xor(v, 32));
      if (l < 16) {
        int col = bcol * 128 + wc * 64 + ni * 16 + l;
        out[(size_t)n * CC + col] = v + pkb[(size_t)n * CC + col];
      }
    }
  }
}

extern "C" void kernel_launch(void* const* d_in, const int* in_sizes, int n_in,
                              void* d_out, int out_size, void* d_ws, size_t ws_size,
                              hipStream_t stream) {
  const float* p = (const float*)d_in[0];   // (N, C, 1, 1)
  const float* o = (const float*)d_in[1];   // (N, M, C, 1, 1)
  const float* W = (const float*)d_in[5];   // (C, 2C)
  const float* b = (const float*)d_in[6];   // (C,)
  float* out = (float*)d_out;               // (N, C, 1, 1)

  char* ws = (char*)d_ws;
  unsigned short* p_bf  = (unsigned short*)ws;                 // 4 MB
  unsigned short* wp_bf = (unsigned short*)(ws + 4194304);     // 2 MB
  unsigned short* wo_bf = (unsigned short*)(ws + 6291456);     // 2 MB
  float*          pkb   = (float*)(ws + 8388608);              // 8 MB

  conv_pw<<<512, 256, 0, stream>>>(p, W, p_bf, wp_bf, wo_bf);
  gemm_pk<<<128, 256, 0, stream>>>(p_bf, wp_bf, b, pkb);
  // main: 512 row tiles x 8 col tiles = 4096 blocks, 256 threads
  gemm_fused<<<4096, 256, 0, stream>>>(o, wo_bf, pkb, out);
}

// Round 13
// 195.838 us; speedup vs baseline: 1.9881x; 1.1247x over previous
//
#include <hip/hip_runtime.h>
#include <hip/hip_bf16.h>

// out[n,d] = b[d] + pk[n,d] + max_m ok[n,m,d]
//   pk = p @ Wp^T  (2048x1024,  K=1024)   -- small 128-tile kernel
//   ok = o @ Wo^T  (65536x1024, K=1024)   -- fused-convert 128^2 GEMM
// R13: m97-style SINGLE-buffer 128x128 tile, 256 thr, LDS 32KB
// (A 16KB + B 16KB, 128B rows, full 3-bit XOR swizzle -> 0 conflicts),
// launch_bounds(256,3) -> ~3 independent blocks/CU whose staging stalls
// overlap (m97/m114 mechanism). Fused A f32->bf16 (reg-stage 8x dwordx4
// coalesced -> cvt -> swizzled ds_write_b64). B via global_load_lds with
// inverse-swizzled source. Drain-per-tile vmcnt ledger:
//   tile top: VMCNT(0) retires A(t) (issued 1 tile ago);
//   pre-compute: VMCNT(8) retires B(t) DMA, keeps A(t+1)[8] in flight.

#define NN 2048
#define MM 32
#define CC 1024

typedef __attribute__((ext_vector_type(8))) __bf16 bf16x8;
typedef __attribute__((ext_vector_type(4))) float f32x4;
typedef __attribute__((ext_vector_type(8))) unsigned short u16x8;
typedef __attribute__((ext_vector_type(4))) unsigned short u16x4;

__device__ inline unsigned short f2bf(float f) {
  union { __hip_bfloat16 h; unsigned short u; } v;
  v.h = __float2bfloat16(f);
  return v.u;
}

__device__ inline void gload_lds16(const void* g, void* l) {
  __builtin_amdgcn_global_load_lds(
      (const __attribute__((address_space(1))) void*)g,
      (__attribute__((address_space(3))) void*)l, 16, 0, 0);
}

// ---- convert person_features + split W into Wp/Wo (bf16) ----
__global__ void conv_pw(const float* __restrict__ p, const float* __restrict__ W,
                        unsigned short* __restrict__ pd,
                        unsigned short* __restrict__ wp,
                        unsigned short* __restrict__ wo) {
  const int PG = (NN * CC) / 8;
  const int WG = (CC * 2 * CC) / 8;
  int i = blockIdx.x * blockDim.x + threadIdx.x;
  int stride = gridDim.x * blockDim.x;
  for (; i < PG + WG; i += stride) {
    if (i < PG) {
      const float4* s = reinterpret_cast<const float4*>(p) + (size_t)i * 2;
      float4 a = s[0], b = s[1];
      u16x8 r;
      r[0] = f2bf(a.x); r[1] = f2bf(a.y); r[2] = f2bf(a.z); r[3] = f2bf(a.w);
      r[4] = f2bf(b.x); r[5] = f2bf(b.y); r[6] = f2bf(b.z); r[7] = f2bf(b.w);
      *reinterpret_cast<u16x8*>(pd + (size_t)i * 8) = r;
    } else {
      int f = i - PG;
      int e = f * 8;
      int d = e >> 11;
      int cc = e & 2047;
      const float4* s = reinterpret_cast<const float4*>(W) + (size_t)f * 2;
      float4 a = s[0], b = s[1];
      u16x8 r;
      r[0] = f2bf(a.x); r[1] = f2bf(a.y); r[2] = f2bf(a.z); r[3] = f2bf(a.w);
      r[4] = f2bf(b.x); r[5] = f2bf(b.y); r[6] = f2bf(b.z); r[7] = f2bf(b.w);
      unsigned short* o = (cc < CC) ? (wp + (size_t)d * CC + cc)
                                    : (wo + (size_t)d * CC + (cc - CC));
      *reinterpret_cast<u16x8*>(o) = r;
    }
  }
}

// ---- small 128x128 GEMM for pk+b ----
__global__ void gemm_pk(const unsigned short* __restrict__ A,
                        const unsigned short* __restrict__ B,
                        const float* __restrict__ bvec,
                        float* __restrict__ out) {
  __shared__ unsigned short As[128 * 64];
  __shared__ unsigned short Bs[128 * 64];

  int nb = gridDim.x;
  int chunk = nb >> 3;
  int obid = blockIdx.x;
  int vb = (obid & 7) * chunk + (obid >> 3);
  int bcol = vb & 7;
  int brow = vb >> 3;

  int tid = threadIdx.x;
  int l = tid & 63;
  int wid = tid >> 6;
  int wr = wid >> 1, wc = wid & 1;
  int lr = l & 15;
  int lk = (l >> 4) << 3;

  const unsigned short* gA = A + (size_t)brow * 128 * CC;
  const unsigned short* gB = B + (size_t)bcol * 128 * CC;

  f32x4 acc[4][4] = {};

  for (int kt = 0; kt < 16; ++kt) {
    int k0 = kt * 64;
#pragma unroll
    for (int j = 0; j < 4; ++j) {
      int f = (j * 256 + tid) * 8;
      int r = f >> 6;
      int c = f & 63;
      gload_lds16(gA + (size_t)r * CC + k0 + c, &As[f]);
      gload_lds16(gB + (size_t)r * CC + k0 + c, &Bs[f]);
    }
    __syncthreads();
#pragma unroll
    for (int kk = 0; kk < 2; ++kk) {
      bf16x8 af[4], bfr[4];
#pragma unroll
      for (int mi = 0; mi < 4; ++mi)
        af[mi] = *reinterpret_cast<const bf16x8*>(
            &As[(wr * 64 + mi * 16 + lr) * 64 + kk * 32 + lk]);
#pragma unroll
      for (int ni = 0; ni < 4; ++ni)
        bfr[ni] = *reinterpret_cast<const bf16x8*>(
            &Bs[(wc * 64 + ni * 16 + lr) * 64 + kk * 32 + lk]);
#pragma unroll
      for (int mi = 0; mi < 4; ++mi)
#pragma unroll
        for (int ni = 0; ni < 4; ++ni)
          acc[mi][ni] = __builtin_amdgcn_mfma_f32_16x16x32_bf16(
              af[mi], bfr[ni], acc[mi][ni], 0, 0, 0);
    }
    __syncthreads();
  }

#pragma unroll
  for (int mi = 0; mi < 4; ++mi) {
    int row = brow * 128 + wr * 64 + mi * 16 + (l >> 4) * 4;
#pragma unroll
    for (int ni = 0; ni < 4; ++ni) {
      int col = bcol * 128 + wc * 64 + ni * 16 + lr;
      float bb = bvec[col];
#pragma unroll
      for (int r = 0; r < 4; ++r)
        out[(size_t)(row + r) * CC + col] = acc[mi][ni][r] + bb;
    }
  }
}

// ==================== 128x128 single-buffer fused GEMM (R13) ================
// LDS: A [128 rows x 64 bf16 = 128B rows] @ 0 (16KB); B same @ 16384. 32KB.
// Swizzle: LDS cell (row, chunk16B c) holds logical chunk c ^ (row&7).

#define BARRIER                                      \
  do {                                               \
    asm volatile("" ::: "memory");                   \
    __builtin_amdgcn_s_barrier();                    \
    asm volatile("" ::: "memory");                   \
  } while (0)

#define LGKM0 asm volatile("s_waitcnt lgkmcnt(0)" ::: "memory")
#define VMCNT(n) asm volatile("s_waitcnt vmcnt(" #n ")" ::: "memory")

// B stage: 128x64 bf16 = 16KB; 4 x gload_lds16/thread, inverse-swz source.
// dest elem idx = (j*256+tid)*8 -> row j*32 + (tid>>3), chunk tid&7.
#define STAGE_B(k0)                                                           \
  do {                                                                        \
    _Pragma("unroll") for (int j = 0; j < 4; ++j)                             \
        gload_lds16(gB + (size_t)(j * 32 + brr) * CC + (k0) + bsc,            \
                    lds + 16384 + (j * 256 + tid) * 16);                      \
  } while (0)

// A issue: 128x64 f32 = 32KB; instr j -> rows j*16 + (tid>>4), 16B col tid&15.
#define ISSUE_A(k0)                                                           \
  do {                                                                        \
    _Pragma("unroll") for (int j = 0; j < 8; ++j)                             \
        aL[j] = *reinterpret_cast<const float4*>(                             \
            gAf + (size_t)(j * 16 + arow0) * CC + (k0) + ac4 * 4);            \
  } while (0)

// cvt + swizzled ds_write_b64 into the A region
#define CVT_WRITE_A                                                           \
  do {                                                                        \
    _Pragma("unroll") for (int j = 0; j < 8; ++j) {                           \
      u16x4 r;                                                                \
      r[0] = f2bf(aL[j].x); r[1] = f2bf(aL[j].y);                             \
      r[2] = f2bf(aL[j].z); r[3] = f2bf(aL[j].w);                             \
      *reinterpret_cast<u16x4*>(lds + (j * 16 + arow0) * 128 + aswz) = r;     \
    }                                                                         \
  } while (0)

#define MFMA16X                                                               \
  do {                                                                        \
    __builtin_amdgcn_s_setprio(1);                                            \
    _Pragma("unroll") for (int mi = 0; mi < 4; ++mi)                          \
        _Pragma("unroll") for (int ni = 0; ni < 4; ++ni)                      \
            acc[mi][ni] = __builtin_amdgcn_mfma_f32_16x16x32_bf16(            \
                af[mi], bfr[ni], acc[mi][ni], 0, 0, 0);                       \
    __builtin_amdgcn_s_setprio(0);                                            \
  } while (0)

__global__ __launch_bounds__(256, 3) void gemm_fused(
    const float* __restrict__ A,
    const unsigned short* __restrict__ B,
    const float* __restrict__ pkb,
    float* __restrict__ out) {
  __shared__ char lds[32768];

  int obid = blockIdx.x;                    // 4096 blocks
  int vb = (obid & 7) * 512 + (obid >> 3);  // XCD-contiguous (4096 % 8 == 0)
  int bcol = vb & 7;                        // 8 col tiles (col-fastest: L2 A-reuse)
  int brow = vb >> 3;                       // 512 row tiles

  int tid = threadIdx.x;
  int l = tid & 63;
  int wid = tid >> 6;
  int wr = wid >> 1;   // 0..1 (M half)
  int wc = wid & 1;    // 0..1 (N half)
  int lr = l & 15;
  int g = l >> 4;      // 0..3

  const float* gAf = A + (size_t)brow * 128 * CC;
  const unsigned short* gB = B + (size_t)bcol * 128 * CC;

  // B staging addressing
  int brr = tid >> 3;                            // 0..31
  int bsc = ((tid & 7) ^ ((tid >> 3) & 7)) * 8;  // inverse-swz source col

  // A reg-staging addressing: instr j -> row j*16+arow0, 16B f32 col ac4
  int arow0 = tid >> 4;                      // 0..15  (row&7 == arow0&7)
  int ac4 = tid & 15;                        // 16 chunks of 16B per 256B row
  int aswz = (((ac4 >> 1) ^ (arow0 & 7)) * 16) + (ac4 & 1) * 8;

  // fragment read bases: row R = (wr|wc)*64 + mi*16 + lr; chunk (kk*4+g)^(R&7)
  int axor = lr & 7;
  int a_k0 = (wr * 64 + lr) * 128 + ((g ^ axor) * 16);
  int a_k1 = (wr * 64 + lr) * 128 + (((4 + g) ^ axor) * 16);
  int b_k0 = 16384 + (wc * 64 + lr) * 128 + ((g ^ axor) * 16);
  int b_k1 = 16384 + (wc * 64 + lr) * 128 + (((4 + g) ^ axor) * 16);

  f32x4 acc[4][4] = {};
  bf16x8 af[4], bfr[4];
  float4 aL[8];

  // prologue: issue A(0); loop handles the rest.
  ISSUE_A(0);

#pragma unroll 1
  for (int t = 0; t < 16; ++t) {
    BARRIER;                 // all waves done reading tile t-1's LDS
    VMCNT(0);                // retire A(t) loads (issued one tile ago)
    CVT_WRITE_A;             // A(t) f32 regs -> bf16 LDS (swizzled)
    STAGE_B(t * 64);         // B(t) DMA  [4 vmem]
    if (t + 1 < 16) ISSUE_A((t + 1) * 64);  // [8 vmem, younger]
    LGKM0;                   // our ds_writes visible
    if (t + 1 < 16) { VMCNT(8); } else { VMCNT(0); }  // retire B(t) DMA
    BARRIER;                 // LDS tile t ready for all waves
    // compute kk=0
#pragma unroll
    for (int mi = 0; mi < 4; ++mi)
      af[mi] = *(const bf16x8*)(lds + a_k0 + mi * 2048);
#pragma unroll
    for (int ni = 0; ni < 4; ++ni)
      bfr[ni] = *(const bf16x8*)(lds + b_k0 + ni * 2048);
    LGKM0;
    MFMA16X;
    // compute kk=1
#pragma unroll
    for (int mi = 0; mi < 4; ++mi)
      af[mi] = *(const bf16x8*)(lds + a_k1 + mi * 2048);
#pragma unroll
    for (int ni = 0; ni < 4; ++ni)
      bfr[ni] = *(const bf16x8*)(lds + b_k1 + ni * 2048);
    LGKM0;
    MFMA16X;
  }

  // fused epilogue: max over 32 consecutive A-rows per n, + pkb
#pragma unroll
  for (int a = 0; a < 2; ++a) {
    int n = brow * 4 + wr * 2 + a;
#pragma unroll
    for (int ni = 0; ni < 4; ++ni) {
      float v = -3.402823466e38f;
#pragma unroll
      for (int mi = 2 * a; mi < 2 * a + 2; ++mi)
#pragma unroll
        for (int r = 0; r < 4; ++r) v = fmaxf(v, acc[mi][ni][r]);
      v = fmaxf(v, __shfl_xor(v, 16));
      v = fmaxf(v, __shfl_xor(v, 32));
      if (l < 16) {
        int col = bcol * 128 + wc * 64 + ni * 16 + l;
        out[(size_t)n * CC + col] = v + pkb[(size_t)n * CC + col];
      }
    }
  }
}

extern "C" void kernel_launch(void* const* d_in, const int* in_sizes, int n_in,
                              void* d_out, int out_size, void* d_ws, size_t ws_size,
                              hipStream_t stream) {
  const float* p = (const float*)d_in[0];   // (N, C, 1, 1)
  const float* o = (const float*)d_in[1];   // (N, M, C, 1, 1)
  const float* W = (const float*)d_in[5];   // (C, 2C)
  const float* b = (const float*)d_in[6];   // (C,)
  float* out = (float*)d_out;               // (N, C, 1, 1)

  char* ws = (char*)d_ws;
  unsigned short* p_bf  = (unsigned short*)ws;                 // 4 MB
  unsigned short* wp_bf = (unsigned short*)(ws + 4194304);     // 2 MB
  unsigned short* wo_bf = (unsigned short*)(ws + 6291456);     // 2 MB
  float*          pkb   = (float*)(ws + 8388608);              // 8 MB

  conv_pw<<<512, 256, 0, stream>>>(p, W, p_bf, wp_bf, wo_bf);
  gemm_pk<<<128, 256, 0, stream>>>(p_bf, wp_bf, b, pkb);
  // main: 512 row tiles x 8 col tiles = 4096 blocks, 256 threads
  gemm_fused<<<4096, 256, 0, stream>>>(o, wo_bf, pkb, out);
}